// Round 1
// baseline (5827.107 us; speedup 1.0000x reference)
//
#include <hip/hip_runtime.h>
#include <hip/hip_bf16.h>

#define NN 100000
#define EE 1600000
#define DD 128

// ---------------------------------------------------------------------------
// degree: deg[dst[e]] += 1
__global__ __launch_bounds__(256) void deg_kernel(const int* __restrict__ dst,
                                                  float* __restrict__ deg, int E_) {
    int e = blockIdx.x * 256 + threadIdx.x;
    if (e < E_) atomicAdd(&deg[dst[e]], 1.0f);
}

// deg[i] = 1 / max(deg[i], 1)
__global__ __launch_bounds__(256) void invdeg_kernel(float* __restrict__ deg, int n) {
    int i = blockIdx.x * 256 + threadIdx.x;
    if (i < n) deg[i] = 1.0f / fmaxf(deg[i], 1.0f);
}

// ---------------------------------------------------------------------------
// scatter: agg[dst[e]] += feat[src[e]]   (32 lanes per edge, float4 each)
__global__ __launch_bounds__(256) void scatter_add(const float* __restrict__ feat,
                                                   const int* __restrict__ src,
                                                   const int* __restrict__ dst,
                                                   float* __restrict__ agg, int E_) {
    int t = blockIdx.x * 256 + threadIdx.x;
    int e = t >> 5;
    if (e >= E_) return;
    int l = t & 31;
    int s = src[e];
    int d = dst[e];
    float4 v = ((const float4*)(feat + (size_t)s * DD))[l];
    float* p = agg + (size_t)d * DD + l * 4;
    atomicAdd(p + 0, v.x);
    atomicAdd(p + 1, v.y);
    atomicAdd(p + 2, v.z);
    atomicAdd(p + 3, v.w);
}

// ---------------------------------------------------------------------------
// out[i,:] = (relu?) (agg[i,:]*invdeg[i]) @ Wl + bl + B[i,:] @ Wr
// Block: 256 threads, 32 rows. Thread (g = tid>>7, j = tid&127) computes
// rows [g*16, g*16+16) at column j. LDS rows are broadcast-read (same addr
// across wave -> conflict-free); W columns are L1-resident coalesced loads.
#define GR 32
__global__ __launch_bounds__(256) void gemm_fused(const float* __restrict__ A,
                                                  const float* B,  // may alias out
                                                  const float* __restrict__ invdeg,
                                                  const float* __restrict__ Wl,
                                                  const float* __restrict__ bl,
                                                  const float* __restrict__ Wr,
                                                  float* out, int relu) {
    __shared__ float a_s[GR][DD];
    __shared__ float b_s[GR][DD];
    const int row0 = blockIdx.x * GR;
    const int tid = threadIdx.x;

    // stage 32 rows of A (scaled by invdeg) and B into LDS
    for (int i = tid; i < GR * (DD / 4); i += 256) {  // 1024 float4
        int r = i >> 5;       // row within tile
        int c4 = i & 31;      // float4 column
        int row = row0 + r;
        float s = invdeg[row];
        float4 av = ((const float4*)(A + (size_t)row * DD))[c4];
        av.x *= s; av.y *= s; av.z *= s; av.w *= s;
        ((float4*)a_s[r])[c4] = av;
        ((float4*)b_s[r])[c4] = ((const float4*)(B + (size_t)row * DD))[c4];
    }
    __syncthreads();

    const int j = tid & 127;
    const int g = tid >> 7;
    const int R = GR / 2;  // 16 rows per thread
    const int rbase = g * R;

    float acc[R];
    float bias = bl[j];
#pragma unroll
    for (int r = 0; r < R; r++) acc[r] = bias;

    for (int k0 = 0; k0 < DD; k0 += 16) {
        float wl[16], wr[16];
#pragma unroll
        for (int t = 0; t < 16; t++) {
            wl[t] = Wl[(k0 + t) * DD + j];
            wr[t] = Wr[(k0 + t) * DD + j];
        }
#pragma unroll
        for (int r = 0; r < R; r++) {
#pragma unroll
            for (int t = 0; t < 16; t += 4) {
                float4 a4 = *(const float4*)&a_s[rbase + r][k0 + t];
                float4 b4 = *(const float4*)&b_s[rbase + r][k0 + t];
                acc[r] += a4.x * wl[t] + a4.y * wl[t + 1] + a4.z * wl[t + 2] + a4.w * wl[t + 3];
                acc[r] += b4.x * wr[t] + b4.y * wr[t + 1] + b4.z * wr[t + 2] + b4.w * wr[t + 3];
            }
        }
    }

#pragma unroll
    for (int r = 0; r < R; r++) {
        float v = acc[r];
        if (relu) v = fmaxf(v, 0.0f);
        out[(size_t)(row0 + rbase + r) * DD + j] = v;
    }
}

// ---------------------------------------------------------------------------
extern "C" void kernel_launch(void* const* d_in, const int* in_sizes, int n_in,
                              void* d_out, int out_size, void* d_ws, size_t ws_size,
                              hipStream_t stream) {
    const float* x   = (const float*)d_in[0];
    const int*   ei  = (const int*)d_in[1];
    const float* Wl1 = (const float*)d_in[2];
    const float* bl1 = (const float*)d_in[3];
    const float* Wr1 = (const float*)d_in[4];
    const float* Wl2 = (const float*)d_in[5];
    const float* bl2 = (const float*)d_in[6];
    const float* Wr2 = (const float*)d_in[7];
    float* out = (float*)d_out;

    const int* src = ei;        // edge_index[0]
    const int* dst = ei + EE;   // edge_index[1]

    float* agg = (float*)d_ws;                  // [N,128]
    float* deg = agg + (size_t)NN * DD;         // [N]  (becomes invdeg)

    // zero agg + deg
    hipMemsetAsync(agg, 0, ((size_t)NN * DD + NN) * sizeof(float), stream);

    deg_kernel<<<(EE + 255) / 256, 256, 0, stream>>>(dst, deg, EE);
    invdeg_kernel<<<(NN + 255) / 256, 256, 0, stream>>>(deg, NN);

    // ---- layer 1 ----
    scatter_add<<<(EE * 32) / 256, 256, 0, stream>>>(x, src, dst, agg, EE);
    // h (relu'd) -> d_out
    gemm_fused<<<NN / GR, 256, 0, stream>>>(agg, x, deg, Wl1, bl1, Wr1, out, 1);

    // ---- layer 2 ----
    hipMemsetAsync(agg, 0, (size_t)NN * DD * sizeof(float), stream);
    scatter_add<<<(EE * 32) / 256, 256, 0, stream>>>(out, src, dst, agg, EE);
    gemm_fused<<<NN / GR, 256, 0, stream>>>(agg, out, deg, Wl2, bl2, Wr2, out, 0);
}

// Round 2
// 762.058 us; speedup vs baseline: 7.6465x; 7.6465x over previous
//
#include <hip/hip_runtime.h>
#include <hip/hip_bf16.h>

#define NN 100000
#define EE 1600000
#define DD 128
#define SCAN_TILE 1024           // 256 threads x 4 elems
#define NB_SCAN ((NN + SCAN_TILE - 1) / SCAN_TILE)   // 98

// ---------------------------------------------------------------------------
// degree count (int atomics on 400KB -> L2-resident, cheap)
__global__ __launch_bounds__(256) void deg_count(const int* __restrict__ dst,
                                                 int* __restrict__ deg, int E_) {
    int e = blockIdx.x * 256 + threadIdx.x;
    if (e < E_) atomicAdd(&deg[dst[e]], 1);
}

// ---------------------------------------------------------------------------
// exclusive scan, stage 1: per-block scan of 1024 elems, write block sums
__global__ __launch_bounds__(256) void scan1(const int* __restrict__ in,
                                             int* __restrict__ out,
                                             int* __restrict__ aux, int n) {
    __shared__ int sdata[256];
    const int t = threadIdx.x;
    const int base = blockIdx.x * SCAN_TILE + t * 4;
    int v[4] = {0, 0, 0, 0};
    if (base + 3 < n) {
        int4 u = *(const int4*)(in + base);
        v[0] = u.x; v[1] = u.y; v[2] = u.z; v[3] = u.w;
    } else {
        for (int j = 0; j < 4; j++) if (base + j < n) v[j] = in[base + j];
    }
    int tsum = v[0] + v[1] + v[2] + v[3];
    sdata[t] = tsum;
    __syncthreads();
    for (int off = 1; off < 256; off <<= 1) {
        int add = (t >= off) ? sdata[t - off] : 0;
        __syncthreads();
        sdata[t] += add;
        __syncthreads();
    }
    int excl = sdata[t] - tsum;
    if (t == 0) aux[blockIdx.x] = sdata[255];
    int run = excl;
    for (int j = 0; j < 4; j++) {
        if (base + j < n) out[base + j] = run;
        run += v[j];
    }
}

// stage 2: exclusive scan of the (<=256) block sums in-place
__global__ __launch_bounds__(256) void scan2(int* __restrict__ aux, int nb) {
    __shared__ int sdata[256];
    const int t = threadIdx.x;
    int val = (t < nb) ? aux[t] : 0;
    sdata[t] = val;
    __syncthreads();
    for (int off = 1; off < 256; off <<= 1) {
        int add = (t >= off) ? sdata[t - off] : 0;
        __syncthreads();
        sdata[t] += add;
        __syncthreads();
    }
    if (t < nb) aux[t] = sdata[t] - val;   // exclusive
}

// stage 3: add block offsets; also init cursor = row_start
__global__ __launch_bounds__(256) void scan3(int* __restrict__ row_start,
                                             const int* __restrict__ aux,
                                             int* __restrict__ cursor, int n) {
    int i = blockIdx.x * 256 + threadIdx.x;
    if (i < n) {
        int rs = row_start[i] + aux[i / SCAN_TILE];
        row_start[i] = rs;
        cursor[i] = rs;
    }
}

// ---------------------------------------------------------------------------
// fill CSR: csr[pos] = src[e] grouped by dst
__global__ __launch_bounds__(256) void csr_fill(const int* __restrict__ src,
                                                const int* __restrict__ dst,
                                                int* __restrict__ cursor,
                                                int* __restrict__ csr, int E_) {
    int e = blockIdx.x * 256 + threadIdx.x;
    if (e < E_) {
        int pos = atomicAdd(&cursor[dst[e]], 1);
        csr[pos] = src[e];
    }
}

// ---------------------------------------------------------------------------
// pull-aggregate: one wave per node; mean of neighbor rows -> bf16 agg row
__global__ __launch_bounds__(256) void gather_mean(const float* __restrict__ feat,
                                                   const int* __restrict__ csr,
                                                   const int* __restrict__ row_start,
                                                   const int* __restrict__ degi,
                                                   ushort* __restrict__ aggb, int n) {
    int node = blockIdx.x * 4 + (threadIdx.x >> 6);
    if (node >= n) return;
    int lane = threadIdx.x & 63;
    int rs = row_start[node];
    int d  = degi[node];
    int re = rs + d;
    float ax = 0.f, ay = 0.f;
    int e = rs;
    for (; e + 2 <= re; e += 2) {
        int s0 = csr[e], s1 = csr[e + 1];
        float2 v0 = ((const float2*)(feat + (size_t)s0 * DD))[lane];
        float2 v1 = ((const float2*)(feat + (size_t)s1 * DD))[lane];
        ax += v0.x + v1.x;
        ay += v0.y + v1.y;
    }
    if (e < re) {
        float2 v0 = ((const float2*)(feat + (size_t)csr[e] * DD))[lane];
        ax += v0.x;
        ay += v0.y;
    }
    float inv = 1.0f / fmaxf((float)d, 1.0f);
    ax *= inv; ay *= inv;
    __hip_bfloat162 h2;
    h2.x = __float2bfloat16(ax);
    h2.y = __float2bfloat16(ay);
    ((__hip_bfloat162*)(aggb + (size_t)node * DD))[lane] = h2;
}

// ---------------------------------------------------------------------------
// out[i,:] = (relu?) agg[i,:] @ Wl + bl + B[i,:] @ Wr     (agg already mean'd, bf16)
#define GR 32
__global__ __launch_bounds__(256) void gemm_fused(const ushort* __restrict__ Ab,
                                                  const float* B,  // may alias out
                                                  const float* __restrict__ Wl,
                                                  const float* __restrict__ bl,
                                                  const float* __restrict__ Wr,
                                                  float* out, int relu) {
    __shared__ float a_s[GR][DD];
    __shared__ float b_s[GR][DD];
    const int row0 = blockIdx.x * GR;
    const int tid = threadIdx.x;

    // stage A (bf16 -> f32) : 32 rows x 128 cols = 512 x uint4 (8 bf16 each)
    for (int i = tid; i < GR * (DD / 8); i += 256) {
        int r = i >> 4, q = i & 15;
        uint4 u = ((const uint4*)(Ab + (size_t)(row0 + r) * DD))[q];
        float* dp = &a_s[r][q * 8];
        uint uu[4] = {u.x, u.y, u.z, u.w};
#pragma unroll
        for (int k = 0; k < 4; k++) {
            union { uint b; float f; } lo, hi;
            lo.b = uu[k] << 16;
            hi.b = uu[k] & 0xffff0000u;
            dp[2 * k]     = lo.f;
            dp[2 * k + 1] = hi.f;
        }
    }
    // stage B (f32)
    for (int i = tid; i < GR * (DD / 4); i += 256) {
        int r = i >> 5, c4 = i & 31;
        ((float4*)b_s[r])[c4] = ((const float4*)(B + (size_t)(row0 + r) * DD))[c4];
    }
    __syncthreads();

    const int j = tid & 127;
    const int g = tid >> 7;
    const int R = GR / 2;  // 16 rows per thread
    const int rbase = g * R;

    float acc[R];
    float bias = bl[j];
#pragma unroll
    for (int r = 0; r < R; r++) acc[r] = bias;

    for (int k0 = 0; k0 < DD; k0 += 16) {
        float wl[16], wr[16];
#pragma unroll
        for (int t = 0; t < 16; t++) {
            wl[t] = Wl[(k0 + t) * DD + j];
            wr[t] = Wr[(k0 + t) * DD + j];
        }
#pragma unroll
        for (int r = 0; r < R; r++) {
#pragma unroll
            for (int t = 0; t < 16; t += 4) {
                float4 a4 = *(const float4*)&a_s[rbase + r][k0 + t];
                float4 b4 = *(const float4*)&b_s[rbase + r][k0 + t];
                acc[r] += a4.x * wl[t] + a4.y * wl[t + 1] + a4.z * wl[t + 2] + a4.w * wl[t + 3];
                acc[r] += b4.x * wr[t] + b4.y * wr[t + 1] + b4.z * wr[t + 2] + b4.w * wr[t + 3];
            }
        }
    }

#pragma unroll
    for (int r = 0; r < R; r++) {
        float v = acc[r];
        if (relu) v = fmaxf(v, 0.0f);
        out[(size_t)(row0 + rbase + r) * DD + j] = v;
    }
}

// ---------------------------------------------------------------------------
extern "C" void kernel_launch(void* const* d_in, const int* in_sizes, int n_in,
                              void* d_out, int out_size, void* d_ws, size_t ws_size,
                              hipStream_t stream) {
    const float* x   = (const float*)d_in[0];
    const int*   ei  = (const int*)d_in[1];
    const float* Wl1 = (const float*)d_in[2];
    const float* bl1 = (const float*)d_in[3];
    const float* Wr1 = (const float*)d_in[4];
    const float* Wl2 = (const float*)d_in[5];
    const float* bl2 = (const float*)d_in[6];
    const float* Wr2 = (const float*)d_in[7];
    float* out = (float*)d_out;

    const int* src = ei;        // edge_index[0]
    const int* dst = ei + EE;   // edge_index[1]

    // workspace layout (~33 MB)
    char* w = (char*)d_ws;
    ushort* aggb     = (ushort*)w;                 w += (size_t)NN * DD * 2;  // 25.6 MB
    int*    deg      = (int*)w;                    w += (size_t)NN * 4;
    int*    row_start= (int*)w;                    w += (size_t)NN * 4;
    int*    cursor   = (int*)w;                    w += (size_t)NN * 4;
    int*    aux      = (int*)w;                    w += 1024;
    int*    csr      = (int*)w;                    // 6.4 MB

    // ---- CSR build (by destination) ----
    hipMemsetAsync(deg, 0, (size_t)NN * sizeof(int), stream);
    deg_count<<<(EE + 255) / 256, 256, 0, stream>>>(dst, deg, EE);
    scan1<<<NB_SCAN, 256, 0, stream>>>(deg, row_start, aux, NN);
    scan2<<<1, 256, 0, stream>>>(aux, NB_SCAN);
    scan3<<<(NN + 255) / 256, 256, 0, stream>>>(row_start, aux, cursor, NN);
    csr_fill<<<(EE + 255) / 256, 256, 0, stream>>>(src, dst, cursor, csr, EE);

    // ---- layer 1 ----
    gather_mean<<<NN / 4, 256, 0, stream>>>(x, csr, row_start, deg, aggb, NN);
    gemm_fused<<<NN / GR, 256, 0, stream>>>(aggb, x, Wl1, bl1, Wr1, out, 1);

    // ---- layer 2 ----
    gather_mean<<<NN / 4, 256, 0, stream>>>(out, csr, row_start, deg, aggb, NN);
    gemm_fused<<<NN / GR, 256, 0, stream>>>(aggb, out, Wl2, bl2, Wr2, out, 0);
}

// Round 3
// 540.072 us; speedup vs baseline: 10.7895x; 1.4110x over previous
//
#include <hip/hip_runtime.h>
#include <hip/hip_bf16.h>

#define NN 100000
#define EE 1600000
#define DD 128
#define K2 256                    // concatenated K (agg | root)
#define BR 64                     // rows per block
#define SCAN_TILE 1024
#define NB_SCAN ((NN + SCAN_TILE - 1) / SCAN_TILE)   // 98

typedef __bf16 bf16x8 __attribute__((ext_vector_type(8)));
typedef float  f32x4  __attribute__((ext_vector_type(4)));

__device__ __forceinline__ uint f2b1(float f) {   // f32 -> bf16 bits (RNE)
    uint u = __float_as_uint(f);
    return (u + 0x7fffu + ((u >> 16) & 1u)) >> 16;
}
__device__ __forceinline__ uint packbf(float lo, float hi) {
    return f2b1(lo) | (f2b1(hi) << 16);
}
__device__ __forceinline__ float b2f(uint bits16) {
    return __uint_as_float(bits16 << 16);
}

// ---------------------------------------------------------------------------
// CSR build (unchanged from round 2)
__global__ __launch_bounds__(256) void deg_count(const int* __restrict__ dst,
                                                 int* __restrict__ deg, int E_) {
    int e = blockIdx.x * 256 + threadIdx.x;
    if (e < E_) atomicAdd(&deg[dst[e]], 1);
}

__global__ __launch_bounds__(256) void scan1(const int* __restrict__ in,
                                             int* __restrict__ out,
                                             int* __restrict__ aux, int n) {
    __shared__ int sdata[256];
    const int t = threadIdx.x;
    const int base = blockIdx.x * SCAN_TILE + t * 4;
    int v[4] = {0, 0, 0, 0};
    if (base + 3 < n) {
        int4 u = *(const int4*)(in + base);
        v[0] = u.x; v[1] = u.y; v[2] = u.z; v[3] = u.w;
    } else {
        for (int j = 0; j < 4; j++) if (base + j < n) v[j] = in[base + j];
    }
    int tsum = v[0] + v[1] + v[2] + v[3];
    sdata[t] = tsum;
    __syncthreads();
    for (int off = 1; off < 256; off <<= 1) {
        int add = (t >= off) ? sdata[t - off] : 0;
        __syncthreads();
        sdata[t] += add;
        __syncthreads();
    }
    int excl = sdata[t] - tsum;
    if (t == 0) aux[blockIdx.x] = sdata[255];
    int run = excl;
    for (int j = 0; j < 4; j++) {
        if (base + j < n) out[base + j] = run;
        run += v[j];
    }
}

__global__ __launch_bounds__(256) void scan2(int* __restrict__ aux, int nb) {
    __shared__ int sdata[256];
    const int t = threadIdx.x;
    int val = (t < nb) ? aux[t] : 0;
    sdata[t] = val;
    __syncthreads();
    for (int off = 1; off < 256; off <<= 1) {
        int add = (t >= off) ? sdata[t - off] : 0;
        __syncthreads();
        sdata[t] += add;
        __syncthreads();
    }
    if (t < nb) aux[t] = sdata[t] - val;
}

__global__ __launch_bounds__(256) void scan3(int* __restrict__ row_start,
                                             const int* __restrict__ aux,
                                             int* __restrict__ cursor, int n) {
    int i = blockIdx.x * 256 + threadIdx.x;
    if (i < n) {
        int rs = row_start[i] + aux[i / SCAN_TILE];
        row_start[i] = rs;
        cursor[i] = rs;
    }
}

__global__ __launch_bounds__(256) void csr_fill(const int* __restrict__ src,
                                                const int* __restrict__ dst,
                                                int* __restrict__ cursor,
                                                int* __restrict__ csr, int E_) {
    int e = blockIdx.x * 256 + threadIdx.x;
    if (e < E_) {
        int pos = atomicAdd(&cursor[dst[e]], 1);
        csr[pos] = src[e];
    }
}

// ---------------------------------------------------------------------------
// x (f32) -> bf16 table
__global__ __launch_bounds__(256) void conv_bf16(const float* __restrict__ x,
                                                 ushort* __restrict__ xb, int n8) {
    int i = blockIdx.x * 256 + threadIdx.x;
    if (i >= n8) return;
    float4 a = ((const float4*)x)[2 * i];
    float4 b = ((const float4*)x)[2 * i + 1];
    uint4 o;
    o.x = packbf(a.x, a.y);
    o.y = packbf(a.z, a.w);
    o.z = packbf(b.x, b.y);
    o.w = packbf(b.z, b.w);
    ((uint4*)xb)[i] = o;
}

// ---------------------------------------------------------------------------
// weight prep: Wfrag[nt 8][kk 8][lane 64][8 bf16], fragment B[k][n]
// k = kk*32 + (lane>>4)*8 + j ; n = nt*16 + (lane&15);  k<128 -> Wl, else Wr
__global__ __launch_bounds__(256) void wprep(const float* __restrict__ Wl,
                                             const float* __restrict__ Wr,
                                             ushort* __restrict__ wf) {
    int idx = blockIdx.x * 256 + threadIdx.x;   // 4096 total
    if (idx >= 4096) return;
    int l  = idx & 63;
    int kk = (idx >> 6) & 7;
    int nt = idx >> 9;
    int col = nt * 16 + (l & 15);
    int kbase = kk * 32 + (l >> 4) * 8;
    uint o[4];
#pragma unroll
    for (int p = 0; p < 4; p++) {
        int k0 = kbase + 2 * p;
        float v0 = (k0 < 128) ? Wl[k0 * DD + col] : Wr[(k0 - 128) * DD + col];
        int k1 = k0 + 1;
        float v1 = (k1 < 128) ? Wl[k1 * DD + col] : Wr[(k1 - 128) * DD + col];
        o[p] = packbf(v0, v1);
    }
    uint4 u = {o[0], o[1], o[2], o[3]};
    ((uint4*)wf)[idx] = u;
}

// ---------------------------------------------------------------------------
// fused: gather-mean (into LDS) + root copy (into LDS) + MFMA GEMM K=256
// LDS tile: [BR rows][256 bf16] = 32 KB, 16B chunks XOR-swizzled by row&7.
// XF32: feat table is f32 (fallback when ws too small for xb)
// RELU/OUTBF: layer-1 writes relu'd bf16 to hb; layer-2 writes f32 to d_out.
template <bool XF32, bool RELU, bool OUTBF>
__global__ __launch_bounds__(256) void fused_layer(
        const ushort* __restrict__ featb, const float* __restrict__ featf,
        const int* __restrict__ csr, const int* __restrict__ row_start,
        const int* __restrict__ deg, const uint4* __restrict__ wf,
        const float* __restrict__ bl,
        ushort* __restrict__ outb, float* __restrict__ outf) {
    __shared__ __align__(16) ushort a_s[BR * K2];
    char* lds = (char*)a_s;
    const int tid = threadIdx.x;
    const int row0 = blockIdx.x * BR;
    const int w = tid >> 6;
    const int l = tid & 63;

    // ---- phase 1: gather-mean, wave w owns rows w*16 .. w*16+15 (chunks 0..15)
    for (int t = 0; t < 16; ++t) {
        int row = w * 16 + t;
        int node = row0 + row;
        float ax = 0.f, ay = 0.f;
        if (node < NN) {
            int rs = row_start[node];
            int d  = deg[node];
            int re = rs + d;
            int e  = rs;
            for (; e + 4 <= re; e += 4) {
                int s0 = csr[e], s1 = csr[e + 1], s2 = csr[e + 2], s3 = csr[e + 3];
                if (XF32) {
                    float2 v0 = ((const float2*)(featf + (size_t)s0 * DD))[l];
                    float2 v1 = ((const float2*)(featf + (size_t)s1 * DD))[l];
                    float2 v2 = ((const float2*)(featf + (size_t)s2 * DD))[l];
                    float2 v3 = ((const float2*)(featf + (size_t)s3 * DD))[l];
                    ax += (v0.x + v1.x) + (v2.x + v3.x);
                    ay += (v0.y + v1.y) + (v2.y + v3.y);
                } else {
                    uint u0 = ((const uint*)(featb + (size_t)s0 * DD))[l];
                    uint u1 = ((const uint*)(featb + (size_t)s1 * DD))[l];
                    uint u2 = ((const uint*)(featb + (size_t)s2 * DD))[l];
                    uint u3 = ((const uint*)(featb + (size_t)s3 * DD))[l];
                    ax += (b2f(u0 & 0xffff) + b2f(u1 & 0xffff)) +
                          (b2f(u2 & 0xffff) + b2f(u3 & 0xffff));
                    ay += (b2f(u0 >> 16) + b2f(u1 >> 16)) +
                          (b2f(u2 >> 16) + b2f(u3 >> 16));
                }
            }
            for (; e < re; ++e) {
                int s0 = csr[e];
                if (XF32) {
                    float2 v0 = ((const float2*)(featf + (size_t)s0 * DD))[l];
                    ax += v0.x; ay += v0.y;
                } else {
                    uint u0 = ((const uint*)(featb + (size_t)s0 * DD))[l];
                    ax += b2f(u0 & 0xffff); ay += b2f(u0 >> 16);
                }
            }
            float inv = 1.0f / fmaxf((float)d, 1.0f);
            ax *= inv; ay *= inv;
        }
        // lane l covers elements 2l,2l+1 -> chunk l>>2, within (l&3)*4
        int off = row * 512 + ((((l >> 2)) ^ (row & 7)) << 4) + ((l & 3) << 2);
        *(uint*)(lds + off) = packbf(ax, ay);
    }

    // ---- phase 2: root rows into chunks 16..31
    for (int i = tid; i < BR * 16; i += 256) {
        int row = i >> 4;
        int c   = i & 15;            // 16B chunk within root half
        int node = row0 + row;
        if (node >= NN) node = NN - 1;
        uint4 u;
        if (XF32) {
            const float* sp = featf + (size_t)node * DD + c * 8;
            float4 a = *(const float4*)sp;
            float4 b = *(const float4*)(sp + 4);
            u.x = packbf(a.x, a.y); u.y = packbf(a.z, a.w);
            u.z = packbf(b.x, b.y); u.w = packbf(b.z, b.w);
        } else {
            u = ((const uint4*)(featb + (size_t)node * DD))[c];
        }
        int off = row * 512 + (((16 + c) ^ (row & 7)) << 4);
        *(uint4*)(lds + off) = u;
    }

    __syncthreads();

    // ---- phase 3: MFMA. wave w computes rows w*16..+15, all 128 cols, K=256
    f32x4 acc[8] = {};
    const int sub  = l >> 4;            // 0..3
    const int lrow = w * 16 + (l & 15);
    const char* lp = lds + lrow * 512;
    const uint4* wfl = wf + l;
#pragma unroll
    for (int kk = 0; kk < 8; ++kk) {
        int chunk = kk * 4 + sub;
        uint4 araw = *(const uint4*)(lp + ((chunk ^ (lrow & 7)) << 4));
        union { uint4 u; bf16x8 b; } ua; ua.u = araw;
#pragma unroll
        for (int nt = 0; nt < 8; ++nt) {
            uint4 braw = wfl[(nt * 8 + kk) * 64];
            union { uint4 u; bf16x8 b; } ub; ub.u = braw;
            acc[nt] = __builtin_amdgcn_mfma_f32_16x16x32_bf16(ua.b, ub.b, acc[nt], 0, 0, 0);
        }
    }

    // ---- epilogue: D[row=(l>>4)*4+i][col=nt*16+(l&15)]
    const int gr0 = row0 + w * 16 + sub * 4;
#pragma unroll
    for (int nt = 0; nt < 8; ++nt) {
        int col = nt * 16 + (l & 15);
        float bias = bl[col];
#pragma unroll
        for (int i = 0; i < 4; ++i) {
            int r = gr0 + i;
            if (r < NN) {
                float v = acc[nt][i] + bias;
                if (RELU) v = fmaxf(v, 0.0f);
                if (OUTBF) outb[(size_t)r * DD + col] = (ushort)f2b1(v);
                else       outf[(size_t)r * DD + col] = v;
            }
        }
    }
}

// ---------------------------------------------------------------------------
extern "C" void kernel_launch(void* const* d_in, const int* in_sizes, int n_in,
                              void* d_out, int out_size, void* d_ws, size_t ws_size,
                              hipStream_t stream) {
    const float* x   = (const float*)d_in[0];
    const int*   ei  = (const int*)d_in[1];
    const float* Wl1 = (const float*)d_in[2];
    const float* bl1 = (const float*)d_in[3];
    const float* Wr1 = (const float*)d_in[4];
    const float* Wl2 = (const float*)d_in[5];
    const float* bl2 = (const float*)d_in[6];
    const float* Wr2 = (const float*)d_in[7];
    float* out = (float*)d_out;

    const int* src = ei;
    const int* dst = ei + EE;

    const size_t sz_feat = (size_t)NN * DD * 2;   // 25.6 MB
    const size_t sz_int  = (size_t)NN * 4;        // 400 KB
    const size_t sz_wf   = 65536;                 // 64 KB
    const size_t sz_csr  = (size_t)EE * 4;        // 6.4 MB
    const size_t need_full = 2 * sz_feat + 3 * sz_int + 4096 + 2 * sz_wf + sz_csr;
    const bool use_xb = ws_size >= need_full;

    char* w = (char*)d_ws;
    ushort* xb = nullptr;
    if (use_xb) { xb = (ushort*)w; w += sz_feat; }
    ushort* hb       = (ushort*)w; w += sz_feat;
    int* deg         = (int*)w;    w += sz_int;
    int* row_start   = (int*)w;    w += sz_int;
    int* cursor      = (int*)w;    w += sz_int;
    int* aux         = (int*)w;    w += 4096;
    ushort* wf1      = (ushort*)w; w += sz_wf;
    ushort* wf2      = (ushort*)w; w += sz_wf;
    int* csr         = (int*)w;

    // ---- CSR build ----
    hipMemsetAsync(deg, 0, sz_int, stream);
    deg_count<<<(EE + 255) / 256, 256, 0, stream>>>(dst, deg, EE);
    scan1<<<NB_SCAN, 256, 0, stream>>>(deg, row_start, aux, NN);
    scan2<<<1, 256, 0, stream>>>(aux, NB_SCAN);
    scan3<<<(NN + 255) / 256, 256, 0, stream>>>(row_start, aux, cursor, NN);
    csr_fill<<<(EE + 255) / 256, 256, 0, stream>>>(src, dst, cursor, csr, EE);

    // ---- weight prep ----
    wprep<<<16, 256, 0, stream>>>(Wl1, Wr1, wf1);
    wprep<<<16, 256, 0, stream>>>(Wl2, Wr2, wf2);

    const int nblk = (NN + BR - 1) / BR;   // 1563

    // ---- layer 1 ----
    if (use_xb) {
        conv_bf16<<<(NN * DD / 8 + 255) / 256, 256, 0, stream>>>(x, xb, NN * DD / 8);
        fused_layer<false, true, true><<<nblk, 256, 0, stream>>>(
            xb, nullptr, csr, row_start, deg, (const uint4*)wf1, bl1, hb, nullptr);
    } else {
        fused_layer<true, true, true><<<nblk, 256, 0, stream>>>(
            nullptr, x, csr, row_start, deg, (const uint4*)wf1, bl1, hb, nullptr);
    }

    // ---- layer 2 ----
    fused_layer<false, false, false><<<nblk, 256, 0, stream>>>(
        hb, nullptr, csr, row_start, deg, (const uint4*)wf2, bl2, nullptr, out);
}

// Round 4
// 408.092 us; speedup vs baseline: 14.2789x; 1.3234x over previous
//
#include <hip/hip_runtime.h>
#include <hip/hip_bf16.h>

#define NN 100000
#define EE 1600000
#define DD 128
#define K2 256                    // concatenated K (agg | root)
#define BR 64                     // rows per block
#define SCAN_TILE 1024
#define NB_SCAN ((NN + SCAN_TILE - 1) / SCAN_TILE)   // 98

typedef __bf16 bf16x8 __attribute__((ext_vector_type(8)));
typedef float  f32x4  __attribute__((ext_vector_type(4)));

__device__ __forceinline__ uint f2b1(float f) {   // f32 -> bf16 bits (RNE)
    uint u = __float_as_uint(f);
    return (u + 0x7fffu + ((u >> 16) & 1u)) >> 16;
}
__device__ __forceinline__ uint packbf(float lo, float hi) {
    return f2b1(lo) | (f2b1(hi) << 16);
}
__device__ __forceinline__ float b2f(uint bits16) {
    return __uint_as_float(bits16 << 16);
}

// ---------------------------------------------------------------------------
// CSR build
__global__ __launch_bounds__(256) void deg_count(const int* __restrict__ dst,
                                                 int* __restrict__ deg, int E_) {
    int base = (blockIdx.x * 256 + threadIdx.x) * 4;
    if (base + 4 <= E_) {
        int4 d4 = *(const int4*)(dst + base);
        atomicAdd(&deg[d4.x], 1);
        atomicAdd(&deg[d4.y], 1);
        atomicAdd(&deg[d4.z], 1);
        atomicAdd(&deg[d4.w], 1);
    } else {
        for (int j = base; j < E_; ++j) atomicAdd(&deg[dst[j]], 1);
    }
}

__global__ __launch_bounds__(256) void scan1(const int* __restrict__ in,
                                             int* __restrict__ out,
                                             int* __restrict__ aux, int n) {
    __shared__ int sdata[256];
    const int t = threadIdx.x;
    const int base = blockIdx.x * SCAN_TILE + t * 4;
    int v[4] = {0, 0, 0, 0};
    if (base + 3 < n) {
        int4 u = *(const int4*)(in + base);
        v[0] = u.x; v[1] = u.y; v[2] = u.z; v[3] = u.w;
    } else {
        for (int j = 0; j < 4; j++) if (base + j < n) v[j] = in[base + j];
    }
    int tsum = v[0] + v[1] + v[2] + v[3];
    sdata[t] = tsum;
    __syncthreads();
    for (int off = 1; off < 256; off <<= 1) {
        int add = (t >= off) ? sdata[t - off] : 0;
        __syncthreads();
        sdata[t] += add;
        __syncthreads();
    }
    int excl = sdata[t] - tsum;
    if (t == 0) aux[blockIdx.x] = sdata[255];
    int run = excl;
    for (int j = 0; j < 4; j++) {
        if (base + j < n) out[base + j] = run;
        run += v[j];
    }
}

__global__ __launch_bounds__(256) void scan2(int* __restrict__ aux, int nb) {
    __shared__ int sdata[256];
    const int t = threadIdx.x;
    int val = (t < nb) ? aux[t] : 0;
    sdata[t] = val;
    __syncthreads();
    for (int off = 1; off < 256; off <<= 1) {
        int add = (t >= off) ? sdata[t - off] : 0;
        __syncthreads();
        sdata[t] += add;
        __syncthreads();
    }
    if (t < nb) aux[t] = sdata[t] - val;
}

__global__ __launch_bounds__(256) void scan3(int* __restrict__ row_start,
                                             const int* __restrict__ aux,
                                             int* __restrict__ cursor, int n) {
    int i = blockIdx.x * 256 + threadIdx.x;
    if (i < n) {
        int rs = row_start[i] + aux[i / SCAN_TILE];
        row_start[i] = rs;
        cursor[i] = rs;
    }
}

__global__ __launch_bounds__(256) void csr_fill(const int* __restrict__ src,
                                                const int* __restrict__ dst,
                                                int* __restrict__ cursor,
                                                int* __restrict__ csr, int E_) {
    int base = (blockIdx.x * 256 + threadIdx.x) * 4;
    if (base + 4 <= E_) {
        int4 s4 = *(const int4*)(src + base);
        int4 d4 = *(const int4*)(dst + base);
        csr[atomicAdd(&cursor[d4.x], 1)] = s4.x;
        csr[atomicAdd(&cursor[d4.y], 1)] = s4.y;
        csr[atomicAdd(&cursor[d4.z], 1)] = s4.z;
        csr[atomicAdd(&cursor[d4.w], 1)] = s4.w;
    } else {
        for (int j = base; j < E_; ++j) {
            int pos = atomicAdd(&cursor[dst[j]], 1);
            csr[pos] = src[j];
        }
    }
}

// ---------------------------------------------------------------------------
// x (f32) -> bf16 table
__global__ __launch_bounds__(256) void conv_bf16(const float* __restrict__ x,
                                                 ushort* __restrict__ xb, int n8) {
    int i = blockIdx.x * 256 + threadIdx.x;
    if (i >= n8) return;
    float4 a = ((const float4*)x)[2 * i];
    float4 b = ((const float4*)x)[2 * i + 1];
    uint4 o;
    o.x = packbf(a.x, a.y);
    o.y = packbf(a.z, a.w);
    o.z = packbf(b.x, b.y);
    o.w = packbf(b.z, b.w);
    ((uint4*)xb)[i] = o;
}

// ---------------------------------------------------------------------------
// weight prep: Wfrag[nt 8][kk 8][lane 64][8 bf16], fragment B[k][n]
__global__ __launch_bounds__(256) void wprep(const float* __restrict__ Wl,
                                             const float* __restrict__ Wr,
                                             ushort* __restrict__ wf) {
    int idx = blockIdx.x * 256 + threadIdx.x;   // 4096 total
    if (idx >= 4096) return;
    int l  = idx & 63;
    int kk = (idx >> 6) & 7;
    int nt = idx >> 9;
    int col = nt * 16 + (l & 15);
    int kbase = kk * 32 + (l >> 4) * 8;
    uint o[4];
#pragma unroll
    for (int p = 0; p < 4; p++) {
        int k0 = kbase + 2 * p;
        float v0 = (k0 < 128) ? Wl[k0 * DD + col] : Wr[(k0 - 128) * DD + col];
        int k1 = k0 + 1;
        float v1 = (k1 < 128) ? Wl[k1 * DD + col] : Wr[(k1 - 128) * DD + col];
        o[p] = packbf(v0, v1);
    }
    uint4 u = {o[0], o[1], o[2], o[3]};
    ((uint4*)wf)[idx] = u;
}

// ---------------------------------------------------------------------------
// fused: gather-mean (4 concurrent rows/wave, 16B/lane) + root copy + MFMA
#define ACC8(u)  do { \
    acc0 += b2f((u).x & 0xffffu); acc1 += b2f((u).x >> 16); \
    acc2 += b2f((u).y & 0xffffu); acc3 += b2f((u).y >> 16); \
    acc4 += b2f((u).z & 0xffffu); acc5 += b2f((u).z >> 16); \
    acc6 += b2f((u).w & 0xffffu); acc7 += b2f((u).w >> 16); } while (0)

template <bool XF32, bool RELU, bool OUTBF>
__global__ __launch_bounds__(256, 4) void fused_layer(
        const ushort* __restrict__ featb, const float* __restrict__ featf,
        const int* __restrict__ csr, const int* __restrict__ row_start,
        const int* __restrict__ deg, const uint4* __restrict__ wf,
        const float* __restrict__ bl,
        ushort* __restrict__ outb, float* __restrict__ outf) {
    __shared__ __align__(16) ushort a_s[BR * K2];
    char* lds = (char*)a_s;
    const int tid = threadIdx.x;
    const int row0 = blockIdx.x * BR;
    const int w = tid >> 6;
    const int l = tid & 63;
    const int sub = l >> 4;       // row within 4-row group
    const int li  = l & 15;       // 16B chunk within row

    const uint4*  fb4 = (const uint4*)featb;
    const float4* ff4 = (const float4*)featf;

    // ---- phase 1: gather-mean. Wave w owns rows w*16..+15, 4 rows at a time.
    for (int g = 0; g < 4; ++g) {
        const int row  = w * 16 + g * 4 + sub;
        const int node = row0 + row;
        const int cn   = (node < NN) ? node : NN - 1;
        const int d    = (node < NN) ? deg[cn] : 0;
        const int rs   = row_start[cn];

        float acc0 = 0.f, acc1 = 0.f, acc2 = 0.f, acc3 = 0.f;
        float acc4 = 0.f, acc5 = 0.f, acc6 = 0.f, acc7 = 0.f;

        int i0 = (0 < d) ? csr[rs + 0] : 0;
        int i1 = (1 < d) ? csr[rs + 1] : 0;
        int i2 = (2 < d) ? csr[rs + 2] : 0;
        int i3 = (3 < d) ? csr[rs + 3] : 0;
        int e = 0;
        bool run = (__any(d > 0) != 0);
        while (run) {
            const bool more = (__any(e + 4 < d) != 0);
            int j0 = 0, j1 = 0, j2 = 0, j3 = 0;
            if (more) {
                j0 = (e + 4 < d) ? csr[rs + e + 4] : 0;
                j1 = (e + 5 < d) ? csr[rs + e + 5] : 0;
                j2 = (e + 6 < d) ? csr[rs + e + 6] : 0;
                j3 = (e + 7 < d) ? csr[rs + e + 7] : 0;
            }
            if (XF32) {
                float4 z = {0.f, 0.f, 0.f, 0.f};
                float4 a0 = z, b0 = z, a1 = z, b1 = z, a2 = z, b2 = z, a3 = z, b3 = z;
                if (e     < d) { a0 = ff4[(size_t)i0 * 32 + li * 2]; b0 = ff4[(size_t)i0 * 32 + li * 2 + 1]; }
                if (e + 1 < d) { a1 = ff4[(size_t)i1 * 32 + li * 2]; b1 = ff4[(size_t)i1 * 32 + li * 2 + 1]; }
                if (e + 2 < d) { a2 = ff4[(size_t)i2 * 32 + li * 2]; b2 = ff4[(size_t)i2 * 32 + li * 2 + 1]; }
                if (e + 3 < d) { a3 = ff4[(size_t)i3 * 32 + li * 2]; b3 = ff4[(size_t)i3 * 32 + li * 2 + 1]; }
                acc0 += a0.x + a1.x + a2.x + a3.x;
                acc1 += a0.y + a1.y + a2.y + a3.y;
                acc2 += a0.z + a1.z + a2.z + a3.z;
                acc3 += a0.w + a1.w + a2.w + a3.w;
                acc4 += b0.x + b1.x + b2.x + b3.x;
                acc5 += b0.y + b1.y + b2.y + b3.y;
                acc6 += b0.z + b1.z + b2.z + b3.z;
                acc7 += b0.w + b1.w + b2.w + b3.w;
            } else {
                uint4 z = {0u, 0u, 0u, 0u};
                uint4 u0 = z, u1 = z, u2 = z, u3 = z;
                if (e     < d) u0 = fb4[(size_t)i0 * 16 + li];
                if (e + 1 < d) u1 = fb4[(size_t)i1 * 16 + li];
                if (e + 2 < d) u2 = fb4[(size_t)i2 * 16 + li];
                if (e + 3 < d) u3 = fb4[(size_t)i3 * 16 + li];
                ACC8(u0); ACC8(u1); ACC8(u2); ACC8(u3);
            }
            i0 = j0; i1 = j1; i2 = j2; i3 = j3;
            e += 4;
            run = more;
        }

        const float inv = 1.0f / fmaxf((float)d, 1.0f);
        uint4 o;
        o.x = packbf(acc0 * inv, acc1 * inv);
        o.y = packbf(acc2 * inv, acc3 * inv);
        o.z = packbf(acc4 * inv, acc5 * inv);
        o.w = packbf(acc6 * inv, acc7 * inv);
        *(uint4*)(lds + row * 512 + ((li ^ (row & 7)) << 4)) = o;
    }

    // ---- phase 2: root rows into chunks 16..31
    for (int i = tid; i < BR * 16; i += 256) {
        int row = i >> 4;
        int c   = i & 15;
        int node = row0 + row;
        if (node >= NN) node = NN - 1;
        uint4 u;
        if (XF32) {
            const float* sp = featf + (size_t)node * DD + c * 8;
            float4 a = *(const float4*)sp;
            float4 b = *(const float4*)(sp + 4);
            u.x = packbf(a.x, a.y); u.y = packbf(a.z, a.w);
            u.z = packbf(b.x, b.y); u.w = packbf(b.z, b.w);
        } else {
            u = ((const uint4*)(featb + (size_t)node * DD))[c];
        }
        int off = row * 512 + (((16 + c) ^ (row & 7)) << 4);
        *(uint4*)(lds + off) = u;
    }

    __syncthreads();

    // ---- phase 3: MFMA. wave w computes rows w*16..+15, all 128 cols, K=256
    f32x4 acc[8] = {};
    const int lrow = w * 16 + (l & 15);
    const char* lp = lds + lrow * 512;
    const uint4* wfl = wf + l;
#pragma unroll
    for (int kk = 0; kk < 8; ++kk) {
        int chunk = kk * 4 + sub;
        uint4 araw = *(const uint4*)(lp + ((chunk ^ (lrow & 7)) << 4));
        union { uint4 u; bf16x8 b; } ua; ua.u = araw;
#pragma unroll
        for (int nt = 0; nt < 8; ++nt) {
            uint4 braw = wfl[(nt * 8 + kk) * 64];
            union { uint4 u; bf16x8 b; } ub; ub.u = braw;
            acc[nt] = __builtin_amdgcn_mfma_f32_16x16x32_bf16(ua.b, ub.b, acc[nt], 0, 0, 0);
        }
    }

    // ---- epilogue: D[row=(l>>4)*4+i][col=nt*16+(l&15)]
    const int gr0 = row0 + w * 16 + sub * 4;
#pragma unroll
    for (int nt = 0; nt < 8; ++nt) {
        int col = nt * 16 + (l & 15);
        float bias = bl[col];
#pragma unroll
        for (int i = 0; i < 4; ++i) {
            int r = gr0 + i;
            if (r < NN) {
                float v = acc[nt][i] + bias;
                if (RELU) v = fmaxf(v, 0.0f);
                if (OUTBF) outb[(size_t)r * DD + col] = (ushort)f2b1(v);
                else       outf[(size_t)r * DD + col] = v;
            }
        }
    }
}

// ---------------------------------------------------------------------------
extern "C" void kernel_launch(void* const* d_in, const int* in_sizes, int n_in,
                              void* d_out, int out_size, void* d_ws, size_t ws_size,
                              hipStream_t stream) {
    const float* x   = (const float*)d_in[0];
    const int*   ei  = (const int*)d_in[1];
    const float* Wl1 = (const float*)d_in[2];
    const float* bl1 = (const float*)d_in[3];
    const float* Wr1 = (const float*)d_in[4];
    const float* Wl2 = (const float*)d_in[5];
    const float* bl2 = (const float*)d_in[6];
    const float* Wr2 = (const float*)d_in[7];
    float* out = (float*)d_out;

    const int* src = ei;
    const int* dst = ei + EE;

    const size_t sz_feat = (size_t)NN * DD * 2;   // 25.6 MB
    const size_t sz_int  = (size_t)NN * 4;        // 400 KB
    const size_t sz_wf   = 65536;                 // 64 KB
    const size_t sz_csr  = (size_t)EE * 4;        // 6.4 MB
    const size_t need_full = 2 * sz_feat + 3 * sz_int + 4096 + 2 * sz_wf + sz_csr;
    const bool use_xb = ws_size >= need_full;

    char* w = (char*)d_ws;
    ushort* xb = nullptr;
    if (use_xb) { xb = (ushort*)w; w += sz_feat; }
    ushort* hb       = (ushort*)w; w += sz_feat;
    int* deg         = (int*)w;    w += sz_int;
    int* row_start   = (int*)w;    w += sz_int;
    int* cursor      = (int*)w;    w += sz_int;
    int* aux         = (int*)w;    w += 4096;
    ushort* wf1      = (ushort*)w; w += sz_wf;
    ushort* wf2      = (ushort*)w; w += sz_wf;
    int* csr         = (int*)w;

    // ---- CSR build ----
    hipMemsetAsync(deg, 0, sz_int, stream);
    deg_count<<<(EE / 4 + 255) / 256, 256, 0, stream>>>(dst, deg, EE);
    scan1<<<NB_SCAN, 256, 0, stream>>>(deg, row_start, aux, NN);
    scan2<<<1, 256, 0, stream>>>(aux, NB_SCAN);
    scan3<<<(NN + 255) / 256, 256, 0, stream>>>(row_start, aux, cursor, NN);
    csr_fill<<<(EE / 4 + 255) / 256, 256, 0, stream>>>(src, dst, cursor, csr, EE);

    // ---- weight prep ----
    wprep<<<16, 256, 0, stream>>>(Wl1, Wr1, wf1);
    wprep<<<16, 256, 0, stream>>>(Wl2, Wr2, wf2);

    const int nblk = (NN + BR - 1) / BR;   // 1563

    // ---- layer 1 ----
    if (use_xb) {
        conv_bf16<<<(NN * DD / 8 + 255) / 256, 256, 0, stream>>>(x, xb, NN * DD / 8);
        fused_layer<false, true, true><<<nblk, 256, 0, stream>>>(
            xb, nullptr, csr, row_start, deg, (const uint4*)wf1, bl1, hb, nullptr);
    } else {
        fused_layer<true, true, true><<<nblk, 256, 0, stream>>>(
            nullptr, x, csr, row_start, deg, (const uint4*)wf1, bl1, hb, nullptr);
    }

    // ---- layer 2 ----
    fused_layer<false, false, false><<<nblk, 256, 0, stream>>>(
        hb, nullptr, csr, row_start, deg, (const uint4*)wf2, bl2, nullptr, out);
}

// Round 5
// 258.028 us; speedup vs baseline: 22.5833x; 1.5816x over previous
//
#include <hip/hip_runtime.h>
#include <hip/hip_bf16.h>

#define NN 100000
#define EE 1600000
#define DD 128
#define K2 256                    // concatenated K (agg | root)
#define BR 64                     // rows per block
#define BSHIFT 9
#define BSZ (1 << BSHIFT)                      // 512 nodes / bucket
#define NBUCK ((NN + BSZ - 1) >> BSHIFT)       // 196
#define PASS_E 4096                            // edges per block (passes A/C)
#define NBLK_E ((EE + PASS_E - 1) / PASS_E)    // 391

typedef __bf16 bf16x8 __attribute__((ext_vector_type(8)));
typedef float  f32x4  __attribute__((ext_vector_type(4)));

__device__ __forceinline__ uint f2b1(float f) {   // f32 -> bf16 bits (RNE)
    uint u = __float_as_uint(f);
    return (u + 0x7fffu + ((u >> 16) & 1u)) >> 16;
}
__device__ __forceinline__ uint packbf(float lo, float hi) {
    return f2b1(lo) | (f2b1(hi) << 16);
}
__device__ __forceinline__ float b2f(uint bits16) {
    return __uint_as_float(bits16 << 16);
}

// ---------------------------------------------------------------------------
// pass A: bucket histogram (LDS-staged; ~200 global atomics per block)
__global__ __launch_bounds__(256) void bucket_hist(const int* __restrict__ dst,
                                                   int* __restrict__ bcnt) {
    __shared__ int h[NBUCK];
    for (int i = threadIdx.x; i < NBUCK; i += 256) h[i] = 0;
    __syncthreads();
    const int e0 = blockIdx.x * PASS_E;
#pragma unroll
    for (int it = 0; it < 4; ++it) {
        int e = e0 + it * 1024 + threadIdx.x * 4;
        if (e + 4 <= EE) {
            int4 d = *(const int4*)(dst + e);
            atomicAdd(&h[d.x >> BSHIFT], 1);
            atomicAdd(&h[d.y >> BSHIFT], 1);
            atomicAdd(&h[d.z >> BSHIFT], 1);
            atomicAdd(&h[d.w >> BSHIFT], 1);
        } else {
            for (int j = e; j < EE; ++j) atomicAdd(&h[dst[j] >> BSHIFT], 1);
        }
    }
    __syncthreads();
    for (int i = threadIdx.x; i < NBUCK; i += 256)
        if (h[i]) atomicAdd(&bcnt[i], h[i]);
}

// pass B: exclusive scan of bucket counts -> bbase, bcur
__global__ __launch_bounds__(256) void bucket_scan(const int* __restrict__ bcnt,
                                                   int* __restrict__ bbase,
                                                   int* __restrict__ bcur) {
    __shared__ int s[256];
    const int t = threadIdx.x;
    int v = (t < NBUCK) ? bcnt[t] : 0;
    s[t] = v;
    __syncthreads();
    for (int off = 1; off < 256; off <<= 1) {
        int a = (t >= off) ? s[t - off] : 0;
        __syncthreads();
        s[t] += a;
        __syncthreads();
    }
    if (t < NBUCK) {
        int ex = s[t] - v;
        bbase[t] = ex;
        bcur[t]  = ex;
    }
}

// pass C: scatter packed (dst_local<<17 | src) into per-bucket slices
__global__ __launch_bounds__(256) void bucket_scatter(const int* __restrict__ src,
                                                      const int* __restrict__ dst,
                                                      int* __restrict__ bcur,
                                                      uint* __restrict__ pairs) {
    __shared__ int h[NBUCK];
    __shared__ int lbase[NBUCK];
    for (int i = threadIdx.x; i < NBUCK; i += 256) h[i] = 0;
    __syncthreads();

    const int e0 = blockIdx.x * PASS_E;
    int4 dv[4], sv[4];
#pragma unroll
    for (int it = 0; it < 4; ++it) {
        int e = e0 + it * 1024 + threadIdx.x * 4;
        if (e + 4 <= EE) {
            dv[it] = *(const int4*)(dst + e);
            sv[it] = *(const int4*)(src + e);
            atomicAdd(&h[dv[it].x >> BSHIFT], 1);
            atomicAdd(&h[dv[it].y >> BSHIFT], 1);
            atomicAdd(&h[dv[it].z >> BSHIFT], 1);
            atomicAdd(&h[dv[it].w >> BSHIFT], 1);
        } else {
            int4 z = {-1, -1, -1, -1};
            dv[it] = z; sv[it] = z;
            int* dp = (int*)&dv[it];
            int* sp = (int*)&sv[it];
            for (int j = 0; j < 4; ++j) {
                if (e + j < EE) {
                    dp[j] = dst[e + j];
                    sp[j] = src[e + j];
                    atomicAdd(&h[dp[j] >> BSHIFT], 1);
                }
            }
        }
    }
    __syncthreads();
    for (int i = threadIdx.x; i < NBUCK; i += 256) {
        int c = h[i];
        lbase[i] = c ? atomicAdd(&bcur[i], c) : 0;
    }
    __syncthreads();
    for (int i = threadIdx.x; i < NBUCK; i += 256) h[i] = 0;
    __syncthreads();

#pragma unroll
    for (int it = 0; it < 4; ++it) {
        const int* dp = (const int*)&dv[it];
        const int* sp = (const int*)&sv[it];
#pragma unroll
        for (int j = 0; j < 4; ++j) {
            int d = dp[j];
            if (d >= 0) {
                int b = d >> BSHIFT;
                int off = lbase[b] + atomicAdd(&h[b], 1);
                pairs[off] = ((uint)(d - (b << BSHIFT)) << 17) | (uint)sp[j];
            }
        }
    }
}

// pass D: per-bucket deg/row_start + csr scatter (block-local 32KB window)
__global__ __launch_bounds__(512) void bucket_finalize(const uint* __restrict__ pairs,
                                                       const int* __restrict__ bbase,
                                                       const int* __restrict__ bcnt,
                                                       int* __restrict__ deg,
                                                       int* __restrict__ row_start,
                                                       int* __restrict__ csr) {
    __shared__ int degl[BSZ];
    __shared__ int curl[BSZ];
    const int b  = blockIdx.x;
    const int t  = threadIdx.x;
    const int eb = bbase[b];
    const int ec = bcnt[b];
    const int n0 = b << BSHIFT;
    const int nn = min(BSZ, NN - n0);

    degl[t] = 0;
    __syncthreads();
    for (int i = t; i < ec; i += 512) {
        uint p = pairs[eb + i];
        atomicAdd(&degl[p >> 17], 1);
    }
    __syncthreads();
    int myd = degl[t];
    for (int off = 1; off < BSZ; off <<= 1) {
        int a = (t >= off) ? degl[t - off] : 0;
        __syncthreads();
        degl[t] += a;
        __syncthreads();
    }
    int excl = degl[t] - myd;
    if (t < nn) {
        deg[n0 + t] = myd;
        row_start[n0 + t] = eb + excl;
    }
    curl[t] = excl;
    __syncthreads();
    for (int i = t; i < ec; i += 512) {
        uint p = pairs[eb + i];
        int dl  = p >> 17;
        int pos = atomicAdd(&curl[dl], 1);
        csr[eb + pos] = (int)(p & 0x1ffffu);
    }
}

// ---------------------------------------------------------------------------
// x (f32) -> bf16 table
__global__ __launch_bounds__(256) void conv_bf16(const float* __restrict__ x,
                                                 ushort* __restrict__ xb, int n8) {
    int i = blockIdx.x * 256 + threadIdx.x;
    if (i >= n8) return;
    float4 a = ((const float4*)x)[2 * i];
    float4 b = ((const float4*)x)[2 * i + 1];
    uint4 o;
    o.x = packbf(a.x, a.y);
    o.y = packbf(a.z, a.w);
    o.z = packbf(b.x, b.y);
    o.w = packbf(b.z, b.w);
    ((uint4*)xb)[i] = o;
}

// ---------------------------------------------------------------------------
// weight prep: Wfrag[nt 8][kk 8][lane 64][8 bf16], fragment B[k][n]
__global__ __launch_bounds__(256) void wprep(const float* __restrict__ Wl,
                                             const float* __restrict__ Wr,
                                             ushort* __restrict__ wf) {
    int idx = blockIdx.x * 256 + threadIdx.x;   // 4096 total
    if (idx >= 4096) return;
    int l  = idx & 63;
    int kk = (idx >> 6) & 7;
    int nt = idx >> 9;
    int col = nt * 16 + (l & 15);
    int kbase = kk * 32 + (l >> 4) * 8;
    uint o[4];
#pragma unroll
    for (int p = 0; p < 4; p++) {
        int k0 = kbase + 2 * p;
        float v0 = (k0 < 128) ? Wl[k0 * DD + col] : Wr[(k0 - 128) * DD + col];
        int k1 = k0 + 1;
        float v1 = (k1 < 128) ? Wl[k1 * DD + col] : Wr[(k1 - 128) * DD + col];
        o[p] = packbf(v0, v1);
    }
    uint4 u = {o[0], o[1], o[2], o[3]};
    ((uint4*)wf)[idx] = u;
}

// ---------------------------------------------------------------------------
// fused: gather-mean (4 concurrent rows/wave, 16B/lane) + root copy + MFMA
#define ACC8(u)  do { \
    acc0 += b2f((u).x & 0xffffu); acc1 += b2f((u).x >> 16); \
    acc2 += b2f((u).y & 0xffffu); acc3 += b2f((u).y >> 16); \
    acc4 += b2f((u).z & 0xffffu); acc5 += b2f((u).z >> 16); \
    acc6 += b2f((u).w & 0xffffu); acc7 += b2f((u).w >> 16); } while (0)

template <bool XF32, bool RELU, bool OUTBF>
__global__ __launch_bounds__(256, 4) void fused_layer(
        const ushort* __restrict__ featb, const float* __restrict__ featf,
        const int* __restrict__ csr, const int* __restrict__ row_start,
        const int* __restrict__ deg, const uint4* __restrict__ wf,
        const float* __restrict__ bl,
        ushort* __restrict__ outb, float* __restrict__ outf) {
    __shared__ __align__(16) ushort a_s[BR * K2];
    char* lds = (char*)a_s;
    const int tid = threadIdx.x;
    const int row0 = blockIdx.x * BR;
    const int w = tid >> 6;
    const int l = tid & 63;
    const int sub = l >> 4;       // row within 4-row group
    const int li  = l & 15;       // 16B chunk within row

    const uint4*  fb4 = (const uint4*)featb;
    const float4* ff4 = (const float4*)featf;

    // ---- phase 1: gather-mean. Wave w owns rows w*16..+15, 4 rows at a time.
    for (int g = 0; g < 4; ++g) {
        const int row  = w * 16 + g * 4 + sub;
        const int node = row0 + row;
        const int cn   = (node < NN) ? node : NN - 1;
        const int d    = (node < NN) ? deg[cn] : 0;
        const int rs   = row_start[cn];

        float acc0 = 0.f, acc1 = 0.f, acc2 = 0.f, acc3 = 0.f;
        float acc4 = 0.f, acc5 = 0.f, acc6 = 0.f, acc7 = 0.f;

        int i0 = (0 < d) ? csr[rs + 0] : 0;
        int i1 = (1 < d) ? csr[rs + 1] : 0;
        int i2 = (2 < d) ? csr[rs + 2] : 0;
        int i3 = (3 < d) ? csr[rs + 3] : 0;
        int e = 0;
        bool run = (__any(d > 0) != 0);
        while (run) {
            const bool more = (__any(e + 4 < d) != 0);
            int j0 = 0, j1 = 0, j2 = 0, j3 = 0;
            if (more) {
                j0 = (e + 4 < d) ? csr[rs + e + 4] : 0;
                j1 = (e + 5 < d) ? csr[rs + e + 5] : 0;
                j2 = (e + 6 < d) ? csr[rs + e + 6] : 0;
                j3 = (e + 7 < d) ? csr[rs + e + 7] : 0;
            }
            if (XF32) {
                float4 z = {0.f, 0.f, 0.f, 0.f};
                float4 a0 = z, b0 = z, a1 = z, b1 = z, a2 = z, b2 = z, a3 = z, b3 = z;
                if (e     < d) { a0 = ff4[(size_t)i0 * 32 + li * 2]; b0 = ff4[(size_t)i0 * 32 + li * 2 + 1]; }
                if (e + 1 < d) { a1 = ff4[(size_t)i1 * 32 + li * 2]; b1 = ff4[(size_t)i1 * 32 + li * 2 + 1]; }
                if (e + 2 < d) { a2 = ff4[(size_t)i2 * 32 + li * 2]; b2 = ff4[(size_t)i2 * 32 + li * 2 + 1]; }
                if (e + 3 < d) { a3 = ff4[(size_t)i3 * 32 + li * 2]; b3 = ff4[(size_t)i3 * 32 + li * 2 + 1]; }
                acc0 += a0.x + a1.x + a2.x + a3.x;
                acc1 += a0.y + a1.y + a2.y + a3.y;
                acc2 += a0.z + a1.z + a2.z + a3.z;
                acc3 += a0.w + a1.w + a2.w + a3.w;
                acc4 += b0.x + b1.x + b2.x + b3.x;
                acc5 += b0.y + b1.y + b2.y + b3.y;
                acc6 += b0.z + b1.z + b2.z + b3.z;
                acc7 += b0.w + b1.w + b2.w + b3.w;
            } else {
                uint4 z = {0u, 0u, 0u, 0u};
                uint4 u0 = z, u1 = z, u2 = z, u3 = z;
                if (e     < d) u0 = fb4[(size_t)i0 * 16 + li];
                if (e + 1 < d) u1 = fb4[(size_t)i1 * 16 + li];
                if (e + 2 < d) u2 = fb4[(size_t)i2 * 16 + li];
                if (e + 3 < d) u3 = fb4[(size_t)i3 * 16 + li];
                ACC8(u0); ACC8(u1); ACC8(u2); ACC8(u3);
            }
            i0 = j0; i1 = j1; i2 = j2; i3 = j3;
            e += 4;
            run = more;
        }

        const float inv = 1.0f / fmaxf((float)d, 1.0f);
        uint4 o;
        o.x = packbf(acc0 * inv, acc1 * inv);
        o.y = packbf(acc2 * inv, acc3 * inv);
        o.z = packbf(acc4 * inv, acc5 * inv);
        o.w = packbf(acc6 * inv, acc7 * inv);
        *(uint4*)(lds + row * 512 + ((li ^ (row & 7)) << 4)) = o;
    }

    // ---- phase 2: root rows into chunks 16..31
    for (int i = tid; i < BR * 16; i += 256) {
        int row = i >> 4;
        int c   = i & 15;
        int node = row0 + row;
        if (node >= NN) node = NN - 1;
        uint4 u;
        if (XF32) {
            const float* sp = featf + (size_t)node * DD + c * 8;
            float4 a = *(const float4*)sp;
            float4 b = *(const float4*)(sp + 4);
            u.x = packbf(a.x, a.y); u.y = packbf(a.z, a.w);
            u.z = packbf(b.x, b.y); u.w = packbf(b.z, b.w);
        } else {
            u = ((const uint4*)(featb + (size_t)node * DD))[c];
        }
        int off = row * 512 + (((16 + c) ^ (row & 7)) << 4);
        *(uint4*)(lds + off) = u;
    }

    __syncthreads();

    // ---- phase 3: MFMA. wave w computes rows w*16..+15, all 128 cols, K=256
    f32x4 acc[8] = {};
    const int lrow = w * 16 + (l & 15);
    const char* lp = lds + lrow * 512;
    const uint4* wfl = wf + l;
#pragma unroll
    for (int kk = 0; kk < 8; ++kk) {
        int chunk = kk * 4 + sub;
        uint4 araw = *(const uint4*)(lp + ((chunk ^ (lrow & 7)) << 4));
        union { uint4 u; bf16x8 b; } ua; ua.u = araw;
#pragma unroll
        for (int nt = 0; nt < 8; ++nt) {
            uint4 braw = wfl[(nt * 8 + kk) * 64];
            union { uint4 u; bf16x8 b; } ub; ub.u = braw;
            acc[nt] = __builtin_amdgcn_mfma_f32_16x16x32_bf16(ua.b, ub.b, acc[nt], 0, 0, 0);
        }
    }

    // ---- epilogue: D[row=(l>>4)*4+i][col=nt*16+(l&15)]
    const int gr0 = row0 + w * 16 + sub * 4;
#pragma unroll
    for (int nt = 0; nt < 8; ++nt) {
        int col = nt * 16 + (l & 15);
        float bias = bl[col];
#pragma unroll
        for (int i = 0; i < 4; ++i) {
            int r = gr0 + i;
            if (r < NN) {
                float v = acc[nt][i] + bias;
                if (RELU) v = fmaxf(v, 0.0f);
                if (OUTBF) outb[(size_t)r * DD + col] = (ushort)f2b1(v);
                else       outf[(size_t)r * DD + col] = v;
            }
        }
    }
}

// ---------------------------------------------------------------------------
extern "C" void kernel_launch(void* const* d_in, const int* in_sizes, int n_in,
                              void* d_out, int out_size, void* d_ws, size_t ws_size,
                              hipStream_t stream) {
    const float* x   = (const float*)d_in[0];
    const int*   ei  = (const int*)d_in[1];
    const float* Wl1 = (const float*)d_in[2];
    const float* bl1 = (const float*)d_in[3];
    const float* Wr1 = (const float*)d_in[4];
    const float* Wl2 = (const float*)d_in[5];
    const float* bl2 = (const float*)d_in[6];
    const float* Wr2 = (const float*)d_in[7];
    float* out = (float*)d_out;

    const int* src = ei;
    const int* dst = ei + EE;

    const size_t sz_feat  = (size_t)NN * DD * 2;        // 25.6 MB
    const size_t sz_int   = (size_t)NN * 4;             // 400 KB
    const size_t sz_wf    = 65536;                      // 64 KB
    const size_t sz_csr   = (size_t)EE * 4;             // 6.4 MB
    const size_t sz_pairs = (size_t)EE * 4;             // 6.4 MB (packed)
    const size_t sz_buck  = 4096;                       // bcnt/bbase/bcur (padded)

    // tier A: union(xb | pairs) region; tier B: pairs only, f32 layer-1 gather
    const size_t unionA = sz_feat;                      // >= max(pairs, xb)
    const size_t needA = sz_feat /*hb*/ + unionA + sz_csr + 2 * sz_int +
                         3 * sz_buck + 2 * sz_wf;       // ~58.6 MB
    const bool use_xb = ws_size >= needA;

    char* w = (char*)d_ws;
    ushort* hb = (ushort*)w;  w += sz_feat;
    char* ureg = w;           w += use_xb ? unionA : sz_pairs;
    uint* pairs = (uint*)ureg;
    ushort* xb  = (ushort*)ureg;                        // aliases pairs (pairs die first)
    int* csr       = (int*)w;  w += sz_csr;
    int* deg       = (int*)w;  w += sz_int;
    int* row_start = (int*)w;  w += sz_int;
    int* bcnt      = (int*)w;  w += sz_buck;
    int* bbase     = (int*)w;  w += sz_buck;
    int* bcur      = (int*)w;  w += sz_buck;
    ushort* wf1    = (ushort*)w; w += sz_wf;
    ushort* wf2    = (ushort*)w; w += sz_wf;

    // ---- CSR build (bucket counting sort; no big-array scatter) ----
    hipMemsetAsync(bcnt, 0, sz_buck, stream);
    bucket_hist<<<NBLK_E, 256, 0, stream>>>(dst, bcnt);
    bucket_scan<<<1, 256, 0, stream>>>(bcnt, bbase, bcur);
    bucket_scatter<<<NBLK_E, 256, 0, stream>>>(src, dst, bcur, pairs);
    bucket_finalize<<<NBUCK, 512, 0, stream>>>(pairs, bbase, bcnt, deg, row_start, csr);

    // ---- weight prep ----
    wprep<<<16, 256, 0, stream>>>(Wl1, Wr1, wf1);
    wprep<<<16, 256, 0, stream>>>(Wl2, Wr2, wf2);

    const int nblk = (NN + BR - 1) / BR;   // 1563

    // ---- layer 1 ----
    if (use_xb) {
        // pairs are dead after bucket_finalize; xb overlays them
        conv_bf16<<<(NN * DD / 8 + 255) / 256, 256, 0, stream>>>(x, xb, NN * DD / 8);
        fused_layer<false, true, true><<<nblk, 256, 0, stream>>>(
            xb, nullptr, csr, row_start, deg, (const uint4*)wf1, bl1, hb, nullptr);
    } else {
        fused_layer<true, true, true><<<nblk, 256, 0, stream>>>(
            nullptr, x, csr, row_start, deg, (const uint4*)wf1, bl1, hb, nullptr);
    }

    // ---- layer 2 ----
    fused_layer<false, false, false><<<nblk, 256, 0, stream>>>(
        hb, nullptr, csr, row_start, deg, (const uint4*)wf2, bl2, nullptr, out);
}

// Round 6
// 224.555 us; speedup vs baseline: 25.9496x; 1.1491x over previous
//
#include <hip/hip_runtime.h>
#include <hip/hip_bf16.h>

#define NN 100000
#define EE 1600000
#define DD 128
#define K2 256                    // concatenated K (agg | root)
#define BR 64                     // rows per block
#define BSHIFT 9
#define BSZ (1 << BSHIFT)                      // 512 nodes / bucket
#define NBUCK ((NN + BSZ - 1) >> BSHIFT)       // 196
#define PASS_E 4096                            // edges per block (scatter)
#define NBLK_E ((EE + PASS_E - 1) / PASS_E)    // 391
#define PAIR_CAP 12288                         // slice cap per bucket (mean 8163, +45 sigma)
#define CSR_PAD 4096                           // per-bucket row-padding allowance (512*7 max + align)

typedef __bf16 bf16x8 __attribute__((ext_vector_type(8)));
typedef float  f32x4  __attribute__((ext_vector_type(4)));

__device__ __forceinline__ uint f2b1(float f) {   // f32 -> bf16 bits (RNE)
    uint u = __float_as_uint(f);
    return (u + 0x7fffu + ((u >> 16) & 1u)) >> 16;
}
__device__ __forceinline__ uint packbf(float lo, float hi) {
    return f2b1(lo) | (f2b1(hi) << 16);
}
__device__ __forceinline__ void acc2(float2& s, uint u) {
    s.x += __uint_as_float(u << 16);          // even elem
    s.y += __uint_as_float(u & 0xffff0000u);  // odd elem
}
#define ACCU4(u) { acc2(s01, (u).x); acc2(s23, (u).y); acc2(s45, (u).z); acc2(s67, (u).w); }

// ---------------------------------------------------------------------------
// scatter packed (dst_local<<17 | src) into fixed per-bucket slices.
// bcnt must be zero'd; after this kernel bcnt[b] = edge count of bucket b.
__global__ __launch_bounds__(256) void bucket_scatter(const int* __restrict__ src,
                                                      const int* __restrict__ dst,
                                                      int* __restrict__ bcnt,
                                                      uint* __restrict__ pairs) {
    __shared__ int h[NBUCK];
    __shared__ int lbase[NBUCK];
    for (int i = threadIdx.x; i < NBUCK; i += 256) h[i] = 0;
    __syncthreads();

    const int e0 = blockIdx.x * PASS_E;
    int4 dv[4], sv[4];
#pragma unroll
    for (int it = 0; it < 4; ++it) {
        int e = e0 + it * 1024 + threadIdx.x * 4;
        if (e + 4 <= EE) {
            dv[it] = *(const int4*)(dst + e);
            sv[it] = *(const int4*)(src + e);
            atomicAdd(&h[dv[it].x >> BSHIFT], 1);
            atomicAdd(&h[dv[it].y >> BSHIFT], 1);
            atomicAdd(&h[dv[it].z >> BSHIFT], 1);
            atomicAdd(&h[dv[it].w >> BSHIFT], 1);
        } else {
            int4 z = {-1, -1, -1, -1};
            dv[it] = z; sv[it] = z;
            int* dp = (int*)&dv[it];
            int* sp = (int*)&sv[it];
            for (int j = 0; j < 4; ++j) {
                if (e + j < EE) {
                    dp[j] = dst[e + j];
                    sp[j] = src[e + j];
                    atomicAdd(&h[dp[j] >> BSHIFT], 1);
                }
            }
        }
    }
    __syncthreads();
    for (int i = threadIdx.x; i < NBUCK; i += 256) {
        int c = h[i];
        lbase[i] = c ? atomicAdd(&bcnt[i], c) : 0;
    }
    __syncthreads();
    for (int i = threadIdx.x; i < NBUCK; i += 256) h[i] = 0;
    __syncthreads();

#pragma unroll
    for (int it = 0; it < 4; ++it) {
        const int* dp = (const int*)&dv[it];
        const int* sp = (const int*)&sv[it];
#pragma unroll
        for (int j = 0; j < 4; ++j) {
            int d = dp[j];
            if (d >= 0) {
                int b = d >> BSHIFT;
                int off = lbase[b] + atomicAdd(&h[b], 1);
                pairs[(size_t)b * PAIR_CAP + off] =
                    ((uint)(d - (b << BSHIFT)) << 17) | (uint)sp[j];
            }
        }
    }
}

// tiny scan: cbase[b] = round8(exclusive_prefix(bcnt)) + b*CSR_PAD
__global__ __launch_bounds__(256) void bucket_scan(const int* __restrict__ bcnt,
                                                   int* __restrict__ cbase) {
    __shared__ int s[256];
    const int t = threadIdx.x;
    int v = (t < NBUCK) ? bcnt[t] : 0;
    s[t] = v;
    __syncthreads();
    for (int off = 1; off < 256; off <<= 1) {
        int a = (t >= off) ? s[t - off] : 0;
        __syncthreads();
        s[t] += a;
        __syncthreads();
    }
    if (t < NBUCK) {
        int ex = s[t] - v;
        cbase[t] = ((ex + 7) & ~7) + t * CSR_PAD;
    }
}

// per-bucket: deg, 8-aligned padded row_start, csr scatter (block-local window)
__global__ __launch_bounds__(512) void bucket_finalize(const uint* __restrict__ pairs,
                                                       const int* __restrict__ bcnt,
                                                       const int* __restrict__ cbase,
                                                       int* __restrict__ deg,
                                                       int* __restrict__ row_start,
                                                       int* __restrict__ csr) {
    __shared__ int degl[BSZ];
    __shared__ int curl[BSZ];
    const int b  = blockIdx.x;
    const int t  = threadIdx.x;
    const size_t eb = (size_t)b * PAIR_CAP;
    const int ec = bcnt[b];
    const int cb = cbase[b];
    const int n0 = b << BSHIFT;
    const int nn = min(BSZ, NN - n0);

    degl[t] = 0;
    __syncthreads();
    for (int i = t; i < ec; i += 512) {
        uint p = pairs[eb + i];
        atomicAdd(&degl[p >> 17], 1);
    }
    __syncthreads();
    const int myd = degl[t];
    int pd = (myd + 7) & ~7;           // padded row length
    degl[t] = pd;
    __syncthreads();
    for (int off = 1; off < BSZ; off <<= 1) {
        int a = (t >= off) ? degl[t - off] : 0;
        __syncthreads();
        degl[t] += a;
        __syncthreads();
    }
    const int pexcl = degl[t] - pd;
    if (t < nn) {
        deg[n0 + t] = myd;
        row_start[n0 + t] = cb + pexcl;
    }
    curl[t] = pexcl;
    __syncthreads();
    for (int i = t; i < ec; i += 512) {
        uint p = pairs[eb + i];
        int dl  = p >> 17;
        int pos = atomicAdd(&curl[dl], 1);
        csr[cb + pos] = (int)(p & 0x1ffffu);
    }
}

// ---------------------------------------------------------------------------
// x (f32) -> bf16 table
__global__ __launch_bounds__(256) void conv_bf16(const float* __restrict__ x,
                                                 ushort* __restrict__ xb, int n8) {
    int i = blockIdx.x * 256 + threadIdx.x;
    if (i >= n8) return;
    float4 a = ((const float4*)x)[2 * i];
    float4 b = ((const float4*)x)[2 * i + 1];
    uint4 o;
    o.x = packbf(a.x, a.y);
    o.y = packbf(a.z, a.w);
    o.z = packbf(b.x, b.y);
    o.w = packbf(b.z, b.w);
    ((uint4*)xb)[i] = o;
}

// ---------------------------------------------------------------------------
// weight prep: Wfrag[nt 8][kk 8][lane 64][8 bf16], fragment B[k][n]
__global__ __launch_bounds__(256) void wprep(const float* __restrict__ Wl,
                                             const float* __restrict__ Wr,
                                             ushort* __restrict__ wf) {
    int idx = blockIdx.x * 256 + threadIdx.x;   // 4096 total
    if (idx >= 4096) return;
    int l  = idx & 63;
    int kk = (idx >> 6) & 7;
    int nt = idx >> 9;
    int col = nt * 16 + (l & 15);
    int kbase = kk * 32 + (l >> 4) * 8;
    uint o[4];
#pragma unroll
    for (int p = 0; p < 4; p++) {
        int k0 = kbase + 2 * p;
        float v0 = (k0 < 128) ? Wl[k0 * DD + col] : Wr[(k0 - 128) * DD + col];
        int k1 = k0 + 1;
        float v1 = (k1 < 128) ? Wl[k1 * DD + col] : Wr[(k1 - 128) * DD + col];
        o[p] = packbf(v0, v1);
    }
    uint4 u = {o[0], o[1], o[2], o[3]};
    ((uint4*)wf)[idx] = u;
}

// ---------------------------------------------------------------------------
// fused: gather-mean (wave-local, 4 rows x 8-deep pipelined) + root + MFMA.
// No __syncthreads: every phase touches only wave w's rows w*16..w*16+15.
template <bool XF32, bool RELU, bool OUTBF>
__global__ __launch_bounds__(256, 4) void fused_layer(
        const ushort* __restrict__ featb, const float* __restrict__ featf,
        const int* __restrict__ csr, const int* __restrict__ row_start,
        const int* __restrict__ deg, const uint4* __restrict__ wf,
        const float* __restrict__ bl,
        ushort* __restrict__ outb, float* __restrict__ outf) {
    __shared__ __align__(16) ushort a_s[BR * K2];
    char* lds = (char*)a_s;
    const int tid = threadIdx.x;
    const int row0 = blockIdx.x * BR;
    const int w = tid >> 6;
    const int l = tid & 63;
    const int sub = l >> 4;       // row within 4-row group
    const int li  = l & 15;       // 16B chunk within row

    const uint4*  fb4 = (const uint4*)featb;
    const float4* ff4 = (const float4*)featf;

    // ---- phase 1: gather-mean; wave w owns rows w*16..+15, 4 rows at a time
    for (int g = 0; g < 4; ++g) {
        const int row  = w * 16 + g * 4 + sub;
        const int node = row0 + row;
        const int cn   = (node < NN) ? node : NN - 1;
        const int d    = (node < NN) ? deg[cn] : 0;
        const int rs   = row_start[cn];          // 8-aligned
        const int4* c4 = (const int4*)(csr + rs);

        float2 s01 = {0.f, 0.f}, s23 = {0.f, 0.f}, s45 = {0.f, 0.f}, s67 = {0.f, 0.f};

        if (XF32) {
            // depth-4 pipeline, f32 feature rows (2x float4 per lane)
            int4 I0 = c4[0];
            int e = 0;
            bool run = (__any(d > 0) != 0);
            while (run) {
                const bool more = (__any(e + 4 < d) != 0);
                int4 I1 = c4[(e >> 2) + 1];
                float4 z = {0.f, 0.f, 0.f, 0.f};
                float4 a0 = z, b0 = z, a1 = z, b1 = z, a2 = z, b2 = z, a3 = z, b3 = z;
                if (e     < d) { a0 = ff4[(size_t)I0.x * 32 + li * 2]; b0 = ff4[(size_t)I0.x * 32 + li * 2 + 1]; }
                if (e + 1 < d) { a1 = ff4[(size_t)I0.y * 32 + li * 2]; b1 = ff4[(size_t)I0.y * 32 + li * 2 + 1]; }
                if (e + 2 < d) { a2 = ff4[(size_t)I0.z * 32 + li * 2]; b2 = ff4[(size_t)I0.z * 32 + li * 2 + 1]; }
                if (e + 3 < d) { a3 = ff4[(size_t)I0.w * 32 + li * 2]; b3 = ff4[(size_t)I0.w * 32 + li * 2 + 1]; }
                s01.x += a0.x + a1.x + a2.x + a3.x;
                s01.y += a0.y + a1.y + a2.y + a3.y;
                s23.x += a0.z + a1.z + a2.z + a3.z;
                s23.y += a0.w + a1.w + a2.w + a3.w;
                s45.x += b0.x + b1.x + b2.x + b3.x;
                s45.y += b0.y + b1.y + b2.y + b3.y;
                s67.x += b0.z + b1.z + b2.z + b3.z;
                s67.y += b0.w + b1.w + b2.w + b3.w;
                I0 = I1;
                e += 4;
                run = more;
            }
        } else {
            // depth-8 pipeline, bf16 feature rows (1x uint4 per lane)
            int4 I0 = c4[0];
            int4 I1 = c4[1];
            int e = 0;
            bool run = (__any(d > 0) != 0);
            while (run) {
                const bool more = (__any(e + 8 < d) != 0);
                int4 I2 = c4[(e >> 2) + 2];
                int4 I3 = c4[(e >> 2) + 3];
                uint4 z = {0u, 0u, 0u, 0u};
                uint4 u0 = z, u1 = z, u2 = z, u3 = z, u4 = z, u5 = z, u6 = z, u7 = z;
                if (e     < d) u0 = fb4[(size_t)I0.x * 16 + li];
                if (e + 1 < d) u1 = fb4[(size_t)I0.y * 16 + li];
                if (e + 2 < d) u2 = fb4[(size_t)I0.z * 16 + li];
                if (e + 3 < d) u3 = fb4[(size_t)I0.w * 16 + li];
                if (e + 4 < d) u4 = fb4[(size_t)I1.x * 16 + li];
                if (e + 5 < d) u5 = fb4[(size_t)I1.y * 16 + li];
                if (e + 6 < d) u6 = fb4[(size_t)I1.z * 16 + li];
                if (e + 7 < d) u7 = fb4[(size_t)I1.w * 16 + li];
                ACCU4(u0); ACCU4(u1); ACCU4(u2); ACCU4(u3);
                ACCU4(u4); ACCU4(u5); ACCU4(u6); ACCU4(u7);
                I0 = I2; I1 = I3;
                e += 8;
                run = more;
            }
        }

        const float inv = 1.0f / fmaxf((float)d, 1.0f);
        uint4 o;
        o.x = packbf(s01.x * inv, s01.y * inv);
        o.y = packbf(s23.x * inv, s23.y * inv);
        o.z = packbf(s45.x * inv, s45.y * inv);
        o.w = packbf(s67.x * inv, s67.y * inv);
        *(uint4*)(lds + row * 512 + ((li ^ (row & 7)) << 4)) = o;
    }

    // ---- phase 2: root rows into chunks 16..31 (wave-local: own 16 rows)
    for (int i = l; i < 256; i += 64) {
        int row = w * 16 + (i >> 4);
        int c   = i & 15;
        int node = row0 + row;
        if (node >= NN) node = NN - 1;
        uint4 u;
        if (XF32) {
            const float* sp = featf + (size_t)node * DD + c * 8;
            float4 a = *(const float4*)sp;
            float4 b = *(const float4*)(sp + 4);
            u.x = packbf(a.x, a.y); u.y = packbf(a.z, a.w);
            u.z = packbf(b.x, b.y); u.w = packbf(b.z, b.w);
        } else {
            u = ((const uint4*)(featb + (size_t)node * DD))[c];
        }
        int off = row * 512 + (((16 + c) ^ (row & 7)) << 4);
        *(uint4*)(lds + off) = u;
    }

    // no barrier: phase 3 reads only this wave's rows (compiler orders LDS ops)

    // ---- phase 3: MFMA. wave w computes rows w*16..+15, all 128 cols, K=256
    f32x4 acc[8] = {};
    const int lrow = w * 16 + (l & 15);
    const char* lp = lds + lrow * 512;
    const uint4* wfl = wf + l;
#pragma unroll
    for (int kk = 0; kk < 8; ++kk) {
        int chunk = kk * 4 + sub;
        uint4 araw = *(const uint4*)(lp + ((chunk ^ (lrow & 7)) << 4));
        union { uint4 u; bf16x8 b; } ua; ua.u = araw;
#pragma unroll
        for (int nt = 0; nt < 8; ++nt) {
            uint4 braw = wfl[(nt * 8 + kk) * 64];
            union { uint4 u; bf16x8 b; } ub; ub.u = braw;
            acc[nt] = __builtin_amdgcn_mfma_f32_16x16x32_bf16(ua.b, ub.b, acc[nt], 0, 0, 0);
        }
    }

    // ---- epilogue: D[row=(l>>4)*4+i][col=nt*16+(l&15)]
    const int gr0 = row0 + w * 16 + sub * 4;
#pragma unroll
    for (int nt = 0; nt < 8; ++nt) {
        int col = nt * 16 + (l & 15);
        float bias = bl[col];
#pragma unroll
        for (int i = 0; i < 4; ++i) {
            int r = gr0 + i;
            if (r < NN) {
                float v = acc[nt][i] + bias;
                if (RELU) v = fmaxf(v, 0.0f);
                if (OUTBF) outb[(size_t)r * DD + col] = (ushort)f2b1(v);
                else       outf[(size_t)r * DD + col] = v;
            }
        }
    }
}

// ---------------------------------------------------------------------------
extern "C" void kernel_launch(void* const* d_in, const int* in_sizes, int n_in,
                              void* d_out, int out_size, void* d_ws, size_t ws_size,
                              hipStream_t stream) {
    const float* x   = (const float*)d_in[0];
    const int*   ei  = (const int*)d_in[1];
    const float* Wl1 = (const float*)d_in[2];
    const float* bl1 = (const float*)d_in[3];
    const float* Wr1 = (const float*)d_in[4];
    const float* Wl2 = (const float*)d_in[5];
    const float* bl2 = (const float*)d_in[6];
    const float* Wr2 = (const float*)d_in[7];
    float* out = (float*)d_out;

    const int* src = ei;
    const int* dst = ei + EE;

    const size_t sz_feat  = (size_t)NN * DD * 2;                      // 25.6 MB
    const size_t sz_int   = (size_t)NN * 4;                           // 400 KB
    const size_t sz_wf    = 65536;                                    // 64 KB
    const size_t sz_pairs = (size_t)NBUCK * PAIR_CAP * 4;             // 9.63 MB
    const size_t sz_csr   = ((size_t)EE + (size_t)NBUCK * CSR_PAD + 1024) * 4;  // 9.62 MB
    const size_t sz_buck  = 1024;

    // tier A: xb table (bf16 layer-1 gather), xb overlays pairs after CSR build
    const size_t unionA = sz_feat;   // max(xb, pairs)
    const size_t needA  = sz_feat + unionA + sz_csr + 2 * sz_int +
                          2 * sz_buck + 2 * sz_wf;                    // ~61.8 MB
    const bool use_xb = ws_size >= needA;

    char* w = (char*)d_ws;
    ushort* hb = (ushort*)w;  w += sz_feat;
    char* ureg = w;           w += use_xb ? unionA : sz_pairs;
    uint* pairs = (uint*)ureg;
    ushort* xb  = (ushort*)ureg;     // aliases pairs (pairs dead before xb written)
    int* csr       = (int*)w;  w += sz_csr;
    int* deg       = (int*)w;  w += sz_int;
    int* row_start = (int*)w;  w += sz_int;
    int* bcnt      = (int*)w;  w += sz_buck;
    int* cbase     = (int*)w;  w += sz_buck;
    ushort* wf1    = (ushort*)w; w += sz_wf;
    ushort* wf2    = (ushort*)w; w += sz_wf;

    // ---- CSR build: scatter into fixed slices -> tiny scan -> finalize ----
    hipMemsetAsync(bcnt, 0, sz_buck, stream);
    bucket_scatter<<<NBLK_E, 256, 0, stream>>>(src, dst, bcnt, pairs);
    bucket_scan<<<1, 256, 0, stream>>>(bcnt, cbase);
    bucket_finalize<<<NBUCK, 512, 0, stream>>>(pairs, bcnt, cbase, deg, row_start, csr);

    // ---- weight prep ----
    wprep<<<16, 256, 0, stream>>>(Wl1, Wr1, wf1);
    wprep<<<16, 256, 0, stream>>>(Wl2, Wr2, wf2);

    const int nblk = (NN + BR - 1) / BR;   // 1563

    // ---- layer 1 ----
    if (use_xb) {
        conv_bf16<<<(NN * DD / 8 + 255) / 256, 256, 0, stream>>>(x, xb, NN * DD / 8);
        fused_layer<false, true, true><<<nblk, 256, 0, stream>>>(
            xb, nullptr, csr, row_start, deg, (const uint4*)wf1, bl1, hb, nullptr);
    } else {
        fused_layer<true, true, true><<<nblk, 256, 0, stream>>>(
            nullptr, x, csr, row_start, deg, (const uint4*)wf1, bl1, hb, nullptr);
    }

    // ---- layer 2 ----
    fused_layer<false, false, false><<<nblk, 256, 0, stream>>>(
        hb, nullptr, csr, row_start, deg, (const uint4*)wf2, bl2, nullptr, out);
}